// Round 18
// baseline (106.594 us; speedup 1.0000x reference)
//
#include <hip/hip_runtime.h>

#define B_ 8
#define T_ 2048
#define C_ 1024
#define H_ 64
#define BT_ (B_ * T_)

typedef float f32x4 __attribute__((ext_vector_type(4)));
typedef unsigned short u16x4 __attribute__((ext_vector_type(4)));
typedef unsigned short u16x8 __attribute__((ext_vector_type(8)));
typedef __bf16 bf16x8 __attribute__((ext_vector_type(8)));

// f32 -> bf16 round-to-nearest-even
static __device__ __forceinline__ unsigned short f2bf(float f) {
    unsigned int u = __builtin_bit_cast(unsigned int, f);
    u = (u + 0x7FFFu + ((u >> 16) & 1u)) >> 16;
    return (unsigned short)u;
}

static __device__ __forceinline__ f32x4 mfma16(u16x8 a, u16x8 b, f32x4 c) {
    return __builtin_amdgcn_mfma_f32_16x16x32_bf16(
        __builtin_bit_cast(bf16x8, a), __builtin_bit_cast(bf16x8, b), c, 0, 0, 0);
}

// pack 4 f32 -> 4 bf16 (RNE) via v_cvt_pk
static __device__ __forceinline__ void cvtpk4(float a0, float a1, float a2, float a3,
                                              unsigned& d0, unsigned& d1) {
    asm("v_cvt_pk_bf16_f32 %0, %1, %2" : "=v"(d0) : "v"(a0), "v"(a1));
    asm("v_cvt_pk_bf16_f32 %0, %1, %2" : "=v"(d1) : "v"(a2), "v"(a3));
}

// bf16x4 -> f32x4
static __device__ __forceinline__ f32x4 bf4f(u16x4 v) {
    f32x4 r;
    r[0] = __builtin_bit_cast(float, (unsigned)v[0] << 16);
    r[1] = __builtin_bit_cast(float, (unsigned)v[1] << 16);
    r[2] = __builtin_bit_cast(float, (unsigned)v[2] << 16);
    r[3] = __builtin_bit_cast(float, (unsigned)v[3] << 16);
    return r;
}

// async global->LDS DMA, 16B per lane (uintptr_t AS-cast)
static __device__ __forceinline__ void gload_lds16(const void* g, void* l) {
    auto gp = (const __attribute__((address_space(1))) char*)(
        reinterpret_cast<uintptr_t>(g));
    auto lp = (__attribute__((address_space(3))) char*)(
        reinterpret_cast<uintptr_t>(l));
    __builtin_amdgcn_global_load_lds(gp, lp, 16, 0, 0);
}

// partial-count schedule for attention pairs: P(j) = {5,5,4,4,4,4,3,3}
static __device__ __forceinline__ int Pof(int j) {
    return 5 - (j >= 2 ? 1 : 0) - (j >= 6 ? 1 : 0);
}
static __device__ __forceinline__ int offsof(int j) {
    return (j < 2) ? 5 * j : (j < 6 ? 4 * j + 2 : 3 * j + 8);
}

// ---------------------------------------------------------------------------
// Kernel 1: W -> Wt bf16 (verified) + block 0 zeroes the 64 group counters
// used by attn_part's fused combine (runs first in stream -> deterministic
// per call, graph-replay safe).
// ---------------------------------------------------------------------------
__global__ __launch_bounds__(256) void wprep(const float* __restrict__ Wk,
                                             const float* __restrict__ Wq,
                                             const float* __restrict__ Wv,
                                             unsigned short* __restrict__ wt,
                                             int* __restrict__ cnt) {
    if (blockIdx.x == 0 && threadIdx.x < 64) cnt[threadIdx.x] = 0;
    __shared__ float tile[64][65];
    const int arr = blockIdx.x >> 4, ct = blockIdx.x & 15;
    const float* W = (arr == 0) ? Wk : ((arr == 1) ? Wq : Wv);
    const int tid = threadIdx.x;
    {
        int c = tid >> 2, seg = (tid & 3) << 4;
        const float* src = W + (size_t)(ct * 64 + c) * 64 + seg;
#pragma unroll
        for (int j = 0; j < 16; j += 4) {
            f32x4 v4 = *(const f32x4*)(src + j);
            tile[c][seg + j + 0] = v4[0];
            tile[c][seg + j + 1] = v4[1];
            tile[c][seg + j + 2] = v4[2];
            tile[c][seg + j + 3] = v4[3];
        }
    }
    __syncthreads();
    {
        int h = tid >> 2, cs = (tid & 3) << 4;
        unsigned short* dst = wt + (size_t)(arr * 64 + h) * 1024 + ct * 64 + cs;
#pragma unroll
        for (int j = 0; j < 16; ++j) dst[j] = f2bf(tile[cs + j][h]);
    }
}

// ---------------------------------------------------------------------------
// Kernel 2 (v10): proj GEMM — round-16 version (best measured ~28-29us).
// grid 256, 64 m-rows/block as 2x32 tiles sharing each DMA-staged B k-slice.
// ---------------------------------------------------------------------------
__global__ __launch_bounds__(512, 2) void proj_gemm(const float* __restrict__ idx,
                                                    const unsigned short* __restrict__ wt,
                                                    unsigned short* __restrict__ kw,
                                                    unsigned short* __restrict__ qw,
                                                    unsigned short* __restrict__ vtw) {
    __shared__ unsigned short As[2][64 * 64];    // 16 KB (2 m-tiles stacked)
    __shared__ unsigned short Bs[2][192 * 64];   // 48 KB
    const int tid = threadIdx.x;
    const int lane = tid & 63, w = tid >> 6;
    const int g = lane >> 4, l15 = lane & 15;
    const int m0 = blockIdx.x * 64;
    const int ar = tid >> 3, as_ = tid & 7;      // A: 64 rows x 8 16B-units

    f32x4 acc[2][3] = {};    // [mi][nf]
    f32x4 areg[2][2];        // [set][half]

    auto sloadA = [&](int set, int k0) {
        const f32x4* src = (const f32x4*)(idx + (size_t)(m0 + ar) * 1024 + k0 +
                                          ((as_ ^ (ar & 7)) * 8));
        areg[set][0] = src[0];
        areg[set][1] = src[1];
    };
    auto swriteA = [&](int set, int buf) {
        unsigned d0, d1, d2, d3;
        cvtpk4(areg[set][0][0], areg[set][0][1], areg[set][0][2], areg[set][0][3], d0, d1);
        cvtpk4(areg[set][1][0], areg[set][1][1], areg[set][1][2], areg[set][1][3], d2, d3);
        uint4 pk; pk.x = d0; pk.y = d1; pk.z = d2; pk.w = d3;
        *(uint4*)&As[buf][ar * 64 + as_ * 8] = pk;
    };
    auto stageB = [&](int k0, int buf) {
#pragma unroll
        for (int i = 0; i < 3; ++i) {
            int slot0 = i * 512 + w * 64;               // wave-uniform base unit
            int n = i * 64 + w * 8 + (lane >> 3);
            int us = (lane & 7) ^ (lane >> 3);
            gload_lds16(wt + (size_t)n * 1024 + k0 + us * 8,
                        &Bs[buf][slot0 * 8]);
        }
    };

    stageB(0, 0);
    sloadA(0, 0);
    sloadA(1, 64);
    swriteA(0, 0);
    __syncthreads();

    for (int kt = 0; kt < 16; ++kt) {
        const int cur = kt & 1;
        if (kt < 15) stageB((kt + 1) * 64, cur ^ 1);
        if (kt < 14) sloadA(cur, (kt + 2) * 64);
#pragma unroll
        for (int ks = 0; ks < 2; ++ks) {
            u16x8 a0 = *(const u16x8*)&As[cur][((w & 1) * 16 + l15) * 64 +
                                               (((ks * 4 + g) ^ (l15 & 7)) * 8)];
            u16x8 a1 = *(const u16x8*)&As[cur][(32 + (w & 1) * 16 + l15) * 64 +
                                               (((ks * 4 + g) ^ (l15 & 7)) * 8)];
#pragma unroll
            for (int nf = 0; nf < 3; ++nf) {
                int n = (w >> 1) * 48 + nf * 16 + l15;
                u16x8 b = *(const u16x8*)&Bs[cur][n * 64 + (((ks * 4 + g) ^ (n & 7)) * 8)];
                acc[0][nf] = mfma16(a0, b, acc[0][nf]);
                acc[1][nf] = mfma16(a1, b, acc[1][nf]);
            }
        }
        if (kt < 15) swriteA(cur ^ 1, cur ^ 1);
        __syncthreads();
    }

#pragma unroll
    for (int nf = 0; nf < 3; ++nf) {
        int nb = (w >> 1) * 3 + nf;
        int arr = nb >> 2;
        int nloc = ((nb & 3) << 4) + l15;
#pragma unroll
        for (int mi = 0; mi < 2; ++mi) {
            f32x4 ac = acc[mi][nf];
            int row = m0 + mi * 32 + (w & 1) * 16 + g * 4;
            if (arr == 2) {
                u16x4 pk = {f2bf(ac[0]), f2bf(ac[1]), f2bf(ac[2]), f2bf(ac[3])};
                *(u16x4*)&vtw[(size_t)nloc * BT_ + row] = pk;
            } else {
                unsigned short* dst = arr ? qw : kw;
                dst[(size_t)(row + 0) * 64 + nloc] = f2bf(ac[0]);
                dst[(size_t)(row + 1) * 64 + nloc] = f2bf(ac[1]);
                dst[(size_t)(row + 2) * 64 + nloc] = f2bf(ac[2]);
                dst[(size_t)(row + 3) * 64 + nloc] = f2bf(ac[3]);
            }
        }
    }
}

// ---------------------------------------------------------------------------
// Kernel 3 (v11): attention partials + FUSED COMBINE (flash-decode pattern).
// Round-16 v10 body (DMA staging, static-max softmax, bf16 partials); after
// the partial store each block threadfence+atomicAdd its (b,j) counter; the
// LAST of the P(j) blocks re-reads all partials and writes final out rows.
// Saves the separate comb kernel + launch gap. grid 256 x 512.
// ---------------------------------------------------------------------------
__global__ __launch_bounds__(512, 2) void attn_part(const unsigned short* __restrict__ kw,
                                                    const unsigned short* __restrict__ qw,
                                                    const unsigned short* __restrict__ vtw,
                                                    unsigned short* __restrict__ Opart,
                                                    float* __restrict__ lpart,
                                                    float* __restrict__ out,
                                                    int* __restrict__ cnt) {
    __shared__ unsigned short q_s[2][64 * 64];   // 16 KB
    __shared__ unsigned short v_s[2][64 * 64];   // 16 KB
    __shared__ unsigned short p_s[8 * 32 * 64];  // 32 KB (per-wave P transpose)
    __shared__ int lastf;
    const int tid = threadIdx.x;
    const int w = tid >> 6, lane = tid & 63;
    const int g = lane >> 4, l15 = lane & 15;
    const int bid = blockIdx.x;
    const int b = bid & 7;                  // XCD-local batch
    const int rem = bid >> 3;               // 0..31
    const int j = (rem < 10) ? (rem / 5) : (rem < 26 ? (rem - 2) >> 2 : (rem - 8) / 3);
    const int P = Pof(j);
    const int part = rem - offsof(j);
    const size_t base = (size_t)b * T_;
    const int tA0 = 128 * j + 16 * w;
    const int tB0 = 128 * (15 - j) + 16 * w;
    const int nS = 2 * (16 - j);            // s-tiles covering tile B's range
    unsigned short* p_my = p_s + w * 2048;
    const float SCL = 0.125f * 1.44269504f;
    const float MOFF = 16.0f;

    // k fragments (tf=0 -> tile A rows, tf=1 -> tile B rows)
    u16x8 kf[2][2];
#pragma unroll
    for (int tf = 0; tf < 2; ++tf) {
        const unsigned short* kr = kw + (size_t)(base + (tf ? tB0 : tA0) + l15) * 64;
        kf[tf][0] = *(const u16x8*)(kr + g * 8);
        kf[tf][1] = *(const u16x8*)(kr + 32 + g * 8);
    }

    f32x4 o[4][2] = {};
    float l_lane[2] = {0.f, 0.f};

    auto stageQV = [&](int st, int buf) {
        int s0 = st << 6;
        int r = w * 8 + (lane >> 3);
        int us = (lane & 7) ^ (lane >> 3);
        gload_lds16(qw + (size_t)(base + s0 + r) * 64 + us * 8,
                    &q_s[buf][w * 512]);
        gload_lds16(vtw + (size_t)r * BT_ + base + s0 + us * 8,
                    &v_s[buf][w * 512]);
    };

    stageQV(part, 0);
    __syncthreads();

    int i = 0;
    for (int st = part; st < nS; st += P, ++i) {
        const int s0 = st << 6;
        const int buf = i & 1;
        const bool more = (st + P < nS);
        if (more) stageQV(st + P, buf ^ 1);
        const bool dA = (s0 <= tA0 + 15);
        const bool dB = (s0 <= tB0 + 15);

        u16x8 a[2][4];
#pragma unroll
        for (int ks = 0; ks < 2; ++ks)
#pragma unroll
            for (int sf = 0; sf < 4; ++sf)
                a[ks][sf] = *(const u16x8*)&q_s[buf][(sf * 16 + l15) * 64 +
                                                     (((ks * 4 + g) ^ (l15 & 7)) * 8)];

        f32x4 s_[4][2] = {};
        __builtin_amdgcn_s_setprio(1);
        if (dB) {
#pragma unroll
            for (int ks = 0; ks < 2; ++ks)
#pragma unroll
                for (int sf = 0; sf < 4; ++sf)
                    s_[sf][1] = mfma16(a[ks][sf], kf[1][ks], s_[sf][1]);
        }
        if (dA) {
#pragma unroll
            for (int ks = 0; ks < 2; ++ks)
#pragma unroll
                for (int sf = 0; sf < 4; ++sf)
                    s_[sf][0] = mfma16(a[ks][sf], kf[0][ks], s_[sf][0]);
        }
        __builtin_amdgcn_s_setprio(0);

#pragma unroll
        for (int tf_ = 1; tf_ >= 0; --tf_) {
            if (tf_ ? !dB : !dA) continue;
            const int tbase_ = tf_ ? tB0 : tA0;
            float pv[4][4];
#pragma unroll
            for (int sf = 0; sf < 4; ++sf)
#pragma unroll
                for (int r = 0; r < 4; ++r)
                    pv[sf][r] = exp2f(fmaf(s_[sf][tf_][r], SCL, -MOFF));
            if (s0 + 63 > tbase_) {
                const int t_ = tbase_ + l15;
#pragma unroll
                for (int sf = 0; sf < 4; ++sf)
#pragma unroll
                    for (int r = 0; r < 4; ++r) {
                        int sg = s0 + sf * 16 + g * 4 + r;
                        if (sg > t_) pv[sf][r] = 0.f;
                    }
            }
            float lacc = 0.f;
#pragma unroll
            for (int sf = 0; sf < 4; ++sf)
                lacc += (pv[sf][0] + pv[sf][1]) + (pv[sf][2] + pv[sf][3]);
            l_lane[tf_] += lacc;
            const int trow = tf_ * 16 + l15;
#pragma unroll
            for (int sf = 0; sf < 4; ++sf) {
                unsigned r0, r1;
                cvtpk4(pv[sf][0], pv[sf][1], pv[sf][2], pv[sf][3], r0, r1);
                int u16i = (sf * 2 + (g >> 1)) ^ (l15 & 7);
                uint2 pk; pk.x = r0; pk.y = r1;
                *(uint2*)&p_my[trow * 64 + u16i * 8 + (g & 1) * 4] = pk;
            }
        }

        u16x8 vf[2][4];
#pragma unroll
        for (int ks = 0; ks < 2; ++ks)
#pragma unroll
            for (int mf = 0; mf < 4; ++mf)
                vf[ks][mf] = *(const u16x8*)&v_s[buf][(mf * 16 + l15) * 64 +
                                                      (((ks * 4 + g) ^ (l15 & 7)) * 8)];
        __builtin_amdgcn_s_setprio(1);
#pragma unroll
        for (int ks = 0; ks < 2; ++ks) {
            if (dB) {
                u16x8 bp1 = *(const u16x8*)&p_my[(16 + l15) * 64 +
                                                 (((ks * 4 + g) ^ (l15 & 7)) * 8)];
#pragma unroll
                for (int mf = 0; mf < 4; ++mf)
                    o[mf][1] = mfma16(vf[ks][mf], bp1, o[mf][1]);
            }
            if (dA) {
                u16x8 bp0 = *(const u16x8*)&p_my[l15 * 64 +
                                                 (((ks * 4 + g) ^ (l15 & 7)) * 8)];
#pragma unroll
                for (int mf = 0; mf < 4; ++mf)
                    o[mf][0] = mfma16(vf[ks][mf], bp0, o[mf][0]);
            }
        }
        __builtin_amdgcn_s_setprio(0);

        __syncthreads();
    }

    // ---- store partials (bf16) ----
#pragma unroll
    for (int tf = 0; tf < 2; ++tf) {
        float ls = l_lane[tf];
        ls += __shfl_xor(ls, 16);
        ls += __shfl_xor(ls, 32);
        int rl = tf * 128 + w * 16 + l15;     // row_local 0..255
        if (g == 0) lpart[(size_t)bid * 256 + rl] = ls;
#pragma unroll
        for (int mf = 0; mf < 4; ++mf) {
            unsigned r0, r1;
            cvtpk4(o[mf][tf][0], o[mf][tf][1], o[mf][tf][2], o[mf][tf][3], r0, r1);
            uint2 pk; pk.x = r0; pk.y = r1;
            *(uint2*)&Opart[(size_t)bid * 16384 + (size_t)rl * 64 + mf * 16 + g * 4] = pk;
        }
    }

    // ---- fused combine: last block of group (b,j) finishes the rows ----
    __threadfence();                       // release partial stores (device scope)
    if (tid == 0)
        lastf = (atomicAdd(&cnt[b * 8 + j], 1) == P - 1);
    __syncthreads();
    if (!lastf) return;

    {
        const int offs = offsof(j);
        int rl = tid >> 1;                 // 0..255
        int h0 = (tid & 1) * 32;           // 32 cols each
        int tf = rl >> 7, rloc = rl & 127;
        int trow = tf ? (128 * (15 - j) + rloc) : (128 * j + rloc);
        f32x4 acc[8] = {};
        float L = 0.f;
        for (int p = 0; p < P; ++p) {
            int pb = b + 8 * (offs + p);
            const unsigned short* src = Opart + (size_t)pb * 16384 + (size_t)rl * 64 + h0;
            L += lpart[(size_t)pb * 256 + rl];
#pragma unroll
            for (int q = 0; q < 8; ++q)
                acc[q] += bf4f(*(const u16x4*)(src + q * 4));
        }
        float inv = 1.f / L;
        float* orow = out + (base + trow) * 64 + h0;
#pragma unroll
        for (int q = 0; q < 8; ++q)
            *(f32x4*)(orow + q * 4) = acc[q] * inv;
    }
}

// ---------------------------------------------------------------------------
extern "C" void kernel_launch(void* const* d_in, const int* in_sizes, int n_in,
                              void* d_out, int out_size, void* d_ws, size_t ws_size,
                              hipStream_t stream) {
    const float* idx = (const float*)d_in[0];
    const float* Wk = (const float*)d_in[1];
    const float* Wq = (const float*)d_in[2];
    const float* Wv = (const float*)d_in[3];
    float* out = (float*)d_out;

    // ws: bf16 [wt | kw | qw | vtw] (6.7MB); partials at 8MB; counters at 20MB
    unsigned short* wt = (unsigned short*)d_ws;
    unsigned short* kw = wt + 192 * 1024;
    unsigned short* qw = kw + (size_t)BT_ * 64;
    unsigned short* vtw = qw + (size_t)BT_ * 64;
    unsigned short* Opart = (unsigned short*)((char*)d_ws + (8u << 20));  // 8.4 MB bf16
    float* lpart = (float*)((char*)d_ws + (18u << 20));                   // 256 KB f32
    int* cnt = (int*)((char*)d_ws + (20u << 20));                         // 64 ints

    wprep<<<48, 256, 0, stream>>>(Wk, Wq, Wv, wt, cnt);
    proj_gemm<<<256, 512, 0, stream>>>(idx, wt, kw, qw, vtw);
    attn_part<<<256, 512, 0, stream>>>(kw, qw, vtw, Opart, lpart, out, cnt);
}

// Round 19
// 47.851 us; speedup vs baseline: 2.2276x; 2.2276x over previous
//
#include <hip/hip_runtime.h>

#define B_ 8
#define T_ 2048
#define C_ 1024
#define H_ 64
#define BT_ (B_ * T_)

typedef float f32x4 __attribute__((ext_vector_type(4)));
typedef unsigned short u16x4 __attribute__((ext_vector_type(4)));
typedef unsigned short u16x8 __attribute__((ext_vector_type(8)));
typedef __bf16 bf16x8 __attribute__((ext_vector_type(8)));

// f32 -> bf16 round-to-nearest-even
static __device__ __forceinline__ unsigned short f2bf(float f) {
    unsigned int u = __builtin_bit_cast(unsigned int, f);
    u = (u + 0x7FFFu + ((u >> 16) & 1u)) >> 16;
    return (unsigned short)u;
}

static __device__ __forceinline__ f32x4 mfma16(u16x8 a, u16x8 b, f32x4 c) {
    return __builtin_amdgcn_mfma_f32_16x16x32_bf16(
        __builtin_bit_cast(bf16x8, a), __builtin_bit_cast(bf16x8, b), c, 0, 0, 0);
}

// pack 4 f32 -> 4 bf16 (RNE) via v_cvt_pk
static __device__ __forceinline__ void cvtpk4(float a0, float a1, float a2, float a3,
                                              unsigned& d0, unsigned& d1) {
    asm("v_cvt_pk_bf16_f32 %0, %1, %2" : "=v"(d0) : "v"(a0), "v"(a1));
    asm("v_cvt_pk_bf16_f32 %0, %1, %2" : "=v"(d1) : "v"(a2), "v"(a3));
}

// bf16x4 -> f32x4
static __device__ __forceinline__ f32x4 bf4f(u16x4 v) {
    f32x4 r;
    r[0] = __builtin_bit_cast(float, (unsigned)v[0] << 16);
    r[1] = __builtin_bit_cast(float, (unsigned)v[1] << 16);
    r[2] = __builtin_bit_cast(float, (unsigned)v[2] << 16);
    r[3] = __builtin_bit_cast(float, (unsigned)v[3] << 16);
    return r;
}

// async global->LDS DMA, 16B per lane (uintptr_t AS-cast)
static __device__ __forceinline__ void gload_lds16(const void* g, void* l) {
    auto gp = (const __attribute__((address_space(1))) char*)(
        reinterpret_cast<uintptr_t>(g));
    auto lp = (__attribute__((address_space(3))) char*)(
        reinterpret_cast<uintptr_t>(l));
    __builtin_amdgcn_global_load_lds(gp, lp, 16, 0, 0);
}

// partial-count schedule for attention pairs: P(j) = {5,5,4,4,4,4,3,3}
static __device__ __forceinline__ int Pof(int j) {
    return 5 - (j >= 2 ? 1 : 0) - (j >= 6 ? 1 : 0);
}
static __device__ __forceinline__ int offsof(int j) {
    return (j < 2) ? 5 * j : (j < 6 ? 4 * j + 2 : 3 * j + 8);
}

// ---------------------------------------------------------------------------
// Kernel 1: W [1024][64] f32 (x3) -> Wt [192][1024] bf16 (verified)
// ---------------------------------------------------------------------------
__global__ __launch_bounds__(256) void wprep(const float* __restrict__ Wk,
                                             const float* __restrict__ Wq,
                                             const float* __restrict__ Wv,
                                             unsigned short* __restrict__ wt) {
    __shared__ float tile[64][65];
    const int arr = blockIdx.x >> 4, ct = blockIdx.x & 15;
    const float* W = (arr == 0) ? Wk : ((arr == 1) ? Wq : Wv);
    const int tid = threadIdx.x;
    {
        int c = tid >> 2, seg = (tid & 3) << 4;
        const float* src = W + (size_t)(ct * 64 + c) * 64 + seg;
#pragma unroll
        for (int j = 0; j < 16; j += 4) {
            f32x4 v4 = *(const f32x4*)(src + j);
            tile[c][seg + j + 0] = v4[0];
            tile[c][seg + j + 1] = v4[1];
            tile[c][seg + j + 2] = v4[2];
            tile[c][seg + j + 3] = v4[3];
        }
    }
    __syncthreads();
    {
        int h = tid >> 2, cs = (tid & 3) << 4;
        unsigned short* dst = wt + (size_t)(arr * 64 + h) * 1024 + ct * 64 + cs;
#pragma unroll
        for (int j = 0; j < 16; ++j) dst[j] = f2bf(tile[cs + j][h]);
    }
}

// ---------------------------------------------------------------------------
// Kernel 2 (v10): proj GEMM — round-16 exact (best measured). grid 256,
// 64 m-rows/block as 2x32 tiles sharing each DMA-staged B k-slice.
// ---------------------------------------------------------------------------
__global__ __launch_bounds__(512, 2) void proj_gemm(const float* __restrict__ idx,
                                                    const unsigned short* __restrict__ wt,
                                                    unsigned short* __restrict__ kw,
                                                    unsigned short* __restrict__ qw,
                                                    unsigned short* __restrict__ vtw) {
    __shared__ unsigned short As[2][64 * 64];    // 16 KB (2 m-tiles stacked)
    __shared__ unsigned short Bs[2][192 * 64];   // 48 KB
    const int tid = threadIdx.x;
    const int lane = tid & 63, w = tid >> 6;
    const int g = lane >> 4, l15 = lane & 15;
    const int m0 = blockIdx.x * 64;
    const int ar = tid >> 3, as_ = tid & 7;      // A: 64 rows x 8 16B-units

    f32x4 acc[2][3] = {};    // [mi][nf]
    f32x4 areg[2][2];        // [set][half]

    auto sloadA = [&](int set, int k0) {
        const f32x4* src = (const f32x4*)(idx + (size_t)(m0 + ar) * 1024 + k0 +
                                          ((as_ ^ (ar & 7)) * 8));
        areg[set][0] = src[0];
        areg[set][1] = src[1];
    };
    auto swriteA = [&](int set, int buf) {
        unsigned d0, d1, d2, d3;
        cvtpk4(areg[set][0][0], areg[set][0][1], areg[set][0][2], areg[set][0][3], d0, d1);
        cvtpk4(areg[set][1][0], areg[set][1][1], areg[set][1][2], areg[set][1][3], d2, d3);
        uint4 pk; pk.x = d0; pk.y = d1; pk.z = d2; pk.w = d3;
        *(uint4*)&As[buf][ar * 64 + as_ * 8] = pk;
    };
    auto stageB = [&](int k0, int buf) {
#pragma unroll
        for (int i = 0; i < 3; ++i) {
            int slot0 = i * 512 + w * 64;               // wave-uniform base unit
            int n = i * 64 + w * 8 + (lane >> 3);
            int us = (lane & 7) ^ (lane >> 3);
            gload_lds16(wt + (size_t)n * 1024 + k0 + us * 8,
                        &Bs[buf][slot0 * 8]);
        }
    };

    stageB(0, 0);
    sloadA(0, 0);
    sloadA(1, 64);
    swriteA(0, 0);
    __syncthreads();

    for (int kt = 0; kt < 16; ++kt) {
        const int cur = kt & 1;
        if (kt < 15) stageB((kt + 1) * 64, cur ^ 1);
        if (kt < 14) sloadA(cur, (kt + 2) * 64);
#pragma unroll
        for (int ks = 0; ks < 2; ++ks) {
            u16x8 a0 = *(const u16x8*)&As[cur][((w & 1) * 16 + l15) * 64 +
                                               (((ks * 4 + g) ^ (l15 & 7)) * 8)];
            u16x8 a1 = *(const u16x8*)&As[cur][(32 + (w & 1) * 16 + l15) * 64 +
                                               (((ks * 4 + g) ^ (l15 & 7)) * 8)];
#pragma unroll
            for (int nf = 0; nf < 3; ++nf) {
                int n = (w >> 1) * 48 + nf * 16 + l15;
                u16x8 b = *(const u16x8*)&Bs[cur][n * 64 + (((ks * 4 + g) ^ (n & 7)) * 8)];
                acc[0][nf] = mfma16(a0, b, acc[0][nf]);
                acc[1][nf] = mfma16(a1, b, acc[1][nf]);
            }
        }
        if (kt < 15) swriteA(cur ^ 1, cur ^ 1);
        __syncthreads();
    }

#pragma unroll
    for (int nf = 0; nf < 3; ++nf) {
        int nb = (w >> 1) * 3 + nf;
        int arr = nb >> 2;
        int nloc = ((nb & 3) << 4) + l15;
#pragma unroll
        for (int mi = 0; mi < 2; ++mi) {
            f32x4 ac = acc[mi][nf];
            int row = m0 + mi * 32 + (w & 1) * 16 + g * 4;
            if (arr == 2) {
                u16x4 pk = {f2bf(ac[0]), f2bf(ac[1]), f2bf(ac[2]), f2bf(ac[3])};
                *(u16x4*)&vtw[(size_t)nloc * BT_ + row] = pk;
            } else {
                unsigned short* dst = arr ? qw : kw;
                dst[(size_t)(row + 0) * 64 + nloc] = f2bf(ac[0]);
                dst[(size_t)(row + 1) * 64 + nloc] = f2bf(ac[1]);
                dst[(size_t)(row + 2) * 64 + nloc] = f2bf(ac[2]);
                dst[(size_t)(row + 3) * 64 + nloc] = f2bf(ac[3]);
            }
        }
    }
}

// ---------------------------------------------------------------------------
// Kernel 3 (v10): attention partials — round-16 exact (DMA staging + bf16
// partials). grid 256 x 512.
// ---------------------------------------------------------------------------
__global__ __launch_bounds__(512, 2) void attn_part(const unsigned short* __restrict__ kw,
                                                    const unsigned short* __restrict__ qw,
                                                    const unsigned short* __restrict__ vtw,
                                                    unsigned short* __restrict__ Opart,
                                                    float* __restrict__ lpart) {
    __shared__ unsigned short q_s[2][64 * 64];   // 16 KB
    __shared__ unsigned short v_s[2][64 * 64];   // 16 KB
    __shared__ unsigned short p_s[8 * 32 * 64];  // 32 KB (per-wave P transpose)
    const int tid = threadIdx.x;
    const int w = tid >> 6, lane = tid & 63;
    const int g = lane >> 4, l15 = lane & 15;
    const int bid = blockIdx.x;
    const int b = bid & 7;                  // XCD-local batch
    const int rem = bid >> 3;               // 0..31
    const int j = (rem < 10) ? (rem / 5) : (rem < 26 ? (rem - 2) >> 2 : (rem - 8) / 3);
    const int P = Pof(j);
    const int part = rem - offsof(j);
    const size_t base = (size_t)b * T_;
    const int tA0 = 128 * j + 16 * w;
    const int tB0 = 128 * (15 - j) + 16 * w;
    const int nS = 2 * (16 - j);            // s-tiles covering tile B's range
    unsigned short* p_my = p_s + w * 2048;
    const float SCL = 0.125f * 1.44269504f;
    const float MOFF = 16.0f;

    // k fragments (tf=0 -> tile A rows, tf=1 -> tile B rows)
    u16x8 kf[2][2];
#pragma unroll
    for (int tf = 0; tf < 2; ++tf) {
        const unsigned short* kr = kw + (size_t)(base + (tf ? tB0 : tA0) + l15) * 64;
        kf[tf][0] = *(const u16x8*)(kr + g * 8);
        kf[tf][1] = *(const u16x8*)(kr + 32 + g * 8);
    }

    f32x4 o[4][2] = {};
    float l_lane[2] = {0.f, 0.f};

    // DMA staging: wave w covers rows w*8..w*8+7; source unit (l&7)^(r&7).
    auto stageQV = [&](int st, int buf) {
        int s0 = st << 6;
        int r = w * 8 + (lane >> 3);
        int us = (lane & 7) ^ (lane >> 3);
        gload_lds16(qw + (size_t)(base + s0 + r) * 64 + us * 8,
                    &q_s[buf][w * 512]);
        gload_lds16(vtw + (size_t)r * BT_ + base + s0 + us * 8,
                    &v_s[buf][w * 512]);
    };

    stageQV(part, 0);
    __syncthreads();

    int i = 0;
    for (int st = part; st < nS; st += P, ++i) {
        const int s0 = st << 6;
        const int buf = i & 1;
        const bool more = (st + P < nS);
        if (more) stageQV(st + P, buf ^ 1);   // async DMA into back buffer
        const bool dA = (s0 <= tA0 + 15);
        const bool dB = (s0 <= tB0 + 15);

        // ---- a-frags from shared q tile (used by both tf) ----
        u16x8 a[2][4];
#pragma unroll
        for (int ks = 0; ks < 2; ++ks)
#pragma unroll
            for (int sf = 0; sf < 4; ++sf)
                a[ks][sf] = *(const u16x8*)&q_s[buf][(sf * 16 + l15) * 64 +
                                                     (((ks * 4 + g) ^ (l15 & 7)) * 8)];

        // ---- QK^T ----
        f32x4 s_[4][2] = {};
        __builtin_amdgcn_s_setprio(1);
        if (dB) {
#pragma unroll
            for (int ks = 0; ks < 2; ++ks)
#pragma unroll
                for (int sf = 0; sf < 4; ++sf)
                    s_[sf][1] = mfma16(a[ks][sf], kf[1][ks], s_[sf][1]);
        }
        if (dA) {
#pragma unroll
            for (int ks = 0; ks < 2; ++ks)
#pragma unroll
                for (int sf = 0; sf < 4; ++sf)
                    s_[sf][0] = mfma16(a[ks][sf], kf[0][ks], s_[sf][0]);
        }
        __builtin_amdgcn_s_setprio(0);

        // ---- static-max softmax + p pack (verified path) ----
#pragma unroll
        for (int tf_ = 1; tf_ >= 0; --tf_) {
            if (tf_ ? !dB : !dA) continue;
            const int tbase_ = tf_ ? tB0 : tA0;
            float pv[4][4];
#pragma unroll
            for (int sf = 0; sf < 4; ++sf)
#pragma unroll
                for (int r = 0; r < 4; ++r)
                    pv[sf][r] = exp2f(fmaf(s_[sf][tf_][r], SCL, -MOFF));
            if (s0 + 63 > tbase_) {
                const int t_ = tbase_ + l15;
#pragma unroll
                for (int sf = 0; sf < 4; ++sf)
#pragma unroll
                    for (int r = 0; r < 4; ++r) {
                        int sg = s0 + sf * 16 + g * 4 + r;
                        if (sg > t_) pv[sf][r] = 0.f;
                    }
            }
            float lacc = 0.f;
#pragma unroll
            for (int sf = 0; sf < 4; ++sf)
                lacc += (pv[sf][0] + pv[sf][1]) + (pv[sf][2] + pv[sf][3]);
            l_lane[tf_] += lacc;
            const int trow = tf_ * 16 + l15;
#pragma unroll
            for (int sf = 0; sf < 4; ++sf) {
                unsigned r0, r1;
                cvtpk4(pv[sf][0], pv[sf][1], pv[sf][2], pv[sf][3], r0, r1);
                int u16i = (sf * 2 + (g >> 1)) ^ (l15 & 7);
                uint2 pk; pk.x = r0; pk.y = r1;
                *(uint2*)&p_my[trow * 64 + u16i * 8 + (g & 1) * 4] = pk;
            }
        }

        // ---- PV from shared vT tile ----
        u16x8 vf[2][4];
#pragma unroll
        for (int ks = 0; ks < 2; ++ks)
#pragma unroll
            for (int mf = 0; mf < 4; ++mf)
                vf[ks][mf] = *(const u16x8*)&v_s[buf][(mf * 16 + l15) * 64 +
                                                      (((ks * 4 + g) ^ (l15 & 7)) * 8)];
        __builtin_amdgcn_s_setprio(1);
#pragma unroll
        for (int ks = 0; ks < 2; ++ks) {
            if (dB) {
                u16x8 bp1 = *(const u16x8*)&p_my[(16 + l15) * 64 +
                                                 (((ks * 4 + g) ^ (l15 & 7)) * 8)];
#pragma unroll
                for (int mf = 0; mf < 4; ++mf)
                    o[mf][1] = mfma16(vf[ks][mf], bp1, o[mf][1]);
            }
            if (dA) {
                u16x8 bp0 = *(const u16x8*)&p_my[l15 * 64 +
                                                 (((ks * 4 + g) ^ (l15 & 7)) * 8)];
#pragma unroll
                for (int mf = 0; mf < 4; ++mf)
                    o[mf][0] = mfma16(vf[ks][mf], bp0, o[mf][0]);
            }
        }
        __builtin_amdgcn_s_setprio(0);

        __syncthreads();
    }

    // ---- store partials (bf16): O^T lanes col=t, rows h contiguous ----
#pragma unroll
    for (int tf = 0; tf < 2; ++tf) {
        float ls = l_lane[tf];
        ls += __shfl_xor(ls, 16);
        ls += __shfl_xor(ls, 32);
        int rl = tf * 128 + w * 16 + l15;     // row_local 0..255
        if (g == 0) lpart[(size_t)bid * 256 + rl] = ls;
#pragma unroll
        for (int mf = 0; mf < 4; ++mf) {
            unsigned r0, r1;
            cvtpk4(o[mf][tf][0], o[mf][tf][1], o[mf][tf][2], o[mf][tf][3], r0, r1);
            uint2 pk; pk.x = r0; pk.y = r1;
            *(uint2*)&Opart[(size_t)bid * 16384 + (size_t)rl * 64 + mf * 16 + g * 4] = pk;
        }
    }
}

// ---------------------------------------------------------------------------
// Kernel 4: combine P(j) s-partials (bf16 in, f32 out): out = sum(O)/sum(l).
// grid 1024 x 256; thread -> (row, 4 h-cols).
// ---------------------------------------------------------------------------
__global__ __launch_bounds__(256) void attn_comb(const unsigned short* __restrict__ Opart,
                                                 const float* __restrict__ lpart,
                                                 float* __restrict__ out) {
    int gt = blockIdx.x * 256 + threadIdx.x;
    int row = gt >> 4;                // 0..16383 = b*2048 + t
    int h0 = (gt & 15) << 2;
    int b = row >> 11, t = row & 2047;
    int ti = t >> 7, rit = t & 127;
    int j = (ti < 8) ? ti : (15 - ti);
    int tf = (ti < 8) ? 0 : 1;
    int rl = tf * 128 + rit;
    int P = Pof(j), offs = offsof(j);
    f32x4 acc = {};
    float L = 0.f;
    for (int p = 0; p < P; ++p) {
        int pb = b + 8 * (offs + p);
        u16x4 ov = *(const u16x4*)&Opart[(size_t)pb * 16384 + (size_t)rl * 64 + h0];
        acc += bf4f(ov);
        L += lpart[(size_t)pb * 256 + rl];
    }
    float inv = 1.f / L;
    *(f32x4*)&out[(size_t)row * 64 + h0] = acc * inv;
}

// ---------------------------------------------------------------------------
extern "C" void kernel_launch(void* const* d_in, const int* in_sizes, int n_in,
                              void* d_out, int out_size, void* d_ws, size_t ws_size,
                              hipStream_t stream) {
    const float* idx = (const float*)d_in[0];
    const float* Wk = (const float*)d_in[1];
    const float* Wq = (const float*)d_in[2];
    const float* Wv = (const float*)d_in[3];
    float* out = (float*)d_out;

    // ws: bf16 region [wt | kw | qw | vtw] (6.7 MB); partials at 8 MB (bf16 O + f32 l)
    unsigned short* wt = (unsigned short*)d_ws;
    unsigned short* kw = wt + 192 * 1024;
    unsigned short* qw = kw + (size_t)BT_ * 64;
    unsigned short* vtw = qw + (size_t)BT_ * 64;
    unsigned short* Opart = (unsigned short*)((char*)d_ws + (8u << 20));  // 8.4 MB bf16
    float* lpart = (float*)((char*)d_ws + (18u << 20));                   // 256KB f32

    wprep<<<48, 256, 0, stream>>>(Wk, Wq, Wv, wt);
    proj_gemm<<<256, 512, 0, stream>>>(idx, wt, kw, qw, vtw);
    attn_part<<<256, 512, 0, stream>>>(kw, qw, vtw, Opart, lpart);
    attn_comb<<<1024, 256, 0, stream>>>(Opart, lpart, out);
}

// Round 20
// 46.309 us; speedup vs baseline: 2.3018x; 1.0333x over previous
//
#include <hip/hip_runtime.h>

#define B_ 8
#define T_ 2048
#define C_ 1024
#define H_ 64
#define BT_ (B_ * T_)

typedef float f32x4 __attribute__((ext_vector_type(4)));
typedef unsigned short u16x4 __attribute__((ext_vector_type(4)));
typedef unsigned short u16x8 __attribute__((ext_vector_type(8)));
typedef __bf16 bf16x8 __attribute__((ext_vector_type(8)));

// f32 -> bf16 round-to-nearest-even
static __device__ __forceinline__ unsigned short f2bf(float f) {
    unsigned int u = __builtin_bit_cast(unsigned int, f);
    u = (u + 0x7FFFu + ((u >> 16) & 1u)) >> 16;
    return (unsigned short)u;
}

static __device__ __forceinline__ f32x4 mfma16(u16x8 a, u16x8 b, f32x4 c) {
    return __builtin_amdgcn_mfma_f32_16x16x32_bf16(
        __builtin_bit_cast(bf16x8, a), __builtin_bit_cast(bf16x8, b), c, 0, 0, 0);
}

// pack 4 f32 -> 4 bf16 (RNE) via v_cvt_pk
static __device__ __forceinline__ void cvtpk4(float a0, float a1, float a2, float a3,
                                              unsigned& d0, unsigned& d1) {
    asm("v_cvt_pk_bf16_f32 %0, %1, %2" : "=v"(d0) : "v"(a0), "v"(a1));
    asm("v_cvt_pk_bf16_f32 %0, %1, %2" : "=v"(d1) : "v"(a2), "v"(a3));
}

// bf16x4 -> f32x4
static __device__ __forceinline__ f32x4 bf4f(u16x4 v) {
    f32x4 r;
    r[0] = __builtin_bit_cast(float, (unsigned)v[0] << 16);
    r[1] = __builtin_bit_cast(float, (unsigned)v[1] << 16);
    r[2] = __builtin_bit_cast(float, (unsigned)v[2] << 16);
    r[3] = __builtin_bit_cast(float, (unsigned)v[3] << 16);
    return r;
}

// async global->LDS DMA, 16B per lane (uintptr_t AS-cast)
static __device__ __forceinline__ void gload_lds16(const void* g, void* l) {
    auto gp = (const __attribute__((address_space(1))) char*)(
        reinterpret_cast<uintptr_t>(g));
    auto lp = (__attribute__((address_space(3))) char*)(
        reinterpret_cast<uintptr_t>(l));
    __builtin_amdgcn_global_load_lds(gp, lp, 16, 0, 0);
}

// partial-count schedule for attention pairs: P(j) = {5,5,4,4,4,4,3,3}
static __device__ __forceinline__ int Pof(int j) {
    return 5 - (j >= 2 ? 1 : 0) - (j >= 6 ? 1 : 0);
}
static __device__ __forceinline__ int offsof(int j) {
    return (j < 2) ? 5 * j : (j < 6 ? 4 * j + 2 : 3 * j + 8);
}

// ---------------------------------------------------------------------------
// Kernel 1: W [1024][64] f32 (x3) -> Wt [192][1024] bf16 (verified)
// ---------------------------------------------------------------------------
__global__ __launch_bounds__(256) void wprep(const float* __restrict__ Wk,
                                             const float* __restrict__ Wq,
                                             const float* __restrict__ Wv,
                                             unsigned short* __restrict__ wt) {
    __shared__ float tile[64][65];
    const int arr = blockIdx.x >> 4, ct = blockIdx.x & 15;
    const float* W = (arr == 0) ? Wk : ((arr == 1) ? Wq : Wv);
    const int tid = threadIdx.x;
    {
        int c = tid >> 2, seg = (tid & 3) << 4;
        const float* src = W + (size_t)(ct * 64 + c) * 64 + seg;
#pragma unroll
        for (int j = 0; j < 16; j += 4) {
            f32x4 v4 = *(const f32x4*)(src + j);
            tile[c][seg + j + 0] = v4[0];
            tile[c][seg + j + 1] = v4[1];
            tile[c][seg + j + 2] = v4[2];
            tile[c][seg + j + 3] = v4[3];
        }
    }
    __syncthreads();
    {
        int h = tid >> 2, cs = (tid & 3) << 4;
        unsigned short* dst = wt + (size_t)(arr * 64 + h) * 1024 + ct * 64 + cs;
#pragma unroll
        for (int j = 0; j < 16; ++j) dst[j] = f2bf(tile[cs + j][h]);
    }
}

// ---------------------------------------------------------------------------
// Kernel 2 (v11): proj GEMM = v10 + TRIPLE-BUFFERED B + COUNTED vmcnt across
// RAW barriers (guide T4 / AITER pattern — the untried lever). v10's
// __syncthreads() drained vmcnt(0) each step, forcing each B-DMA to complete
// within its issuing step (~300cy compute vs ~1000cy latency -> step pinned
// at latency, 16x ~1.8us = the 29us plateau). Now stageB(kt+2) rides in
// flight across TWO step boundaries: boundary waits vmcnt(5) (leaves this
// step's 3 B-DMA + 2 A-loads outstanding; forces stageB(kt+1) done in every
// wave before its barrier) + lgkmcnt(0) (ds_write visibility) + s_barrier.
// grid 256, 512 thr, LDS 88 KB (1 block/CU).
// ---------------------------------------------------------------------------
__global__ __launch_bounds__(512, 2) void proj_gemm(const float* __restrict__ idx,
                                                    const unsigned short* __restrict__ wt,
                                                    unsigned short* __restrict__ kw,
                                                    unsigned short* __restrict__ qw,
                                                    unsigned short* __restrict__ vtw) {
    __shared__ unsigned short As[2][64 * 64];    // 16 KB (2 m-tiles stacked)
    __shared__ unsigned short Bs[3][192 * 64];   // 72 KB (TRIPLE buffer)
    const int tid = threadIdx.x;
    const int lane = tid & 63, w = tid >> 6;
    const int g = lane >> 4, l15 = lane & 15;
    const int m0 = blockIdx.x * 64;
    const int ar = tid >> 3, as_ = tid & 7;      // A: 64 rows x 8 16B-units

    f32x4 acc[2][3] = {};    // [mi][nf]
    f32x4 areg[2][2];        // [set][half]

    auto sloadA = [&](int set, int k0) {
        const f32x4* src = (const f32x4*)(idx + (size_t)(m0 + ar) * 1024 + k0 +
                                          ((as_ ^ (ar & 7)) * 8));
        areg[set][0] = src[0];
        areg[set][1] = src[1];
    };
    auto swriteA = [&](int set, int buf) {
        unsigned d0, d1, d2, d3;
        cvtpk4(areg[set][0][0], areg[set][0][1], areg[set][0][2], areg[set][0][3], d0, d1);
        cvtpk4(areg[set][1][0], areg[set][1][1], areg[set][1][2], areg[set][1][3], d2, d3);
        uint4 pk; pk.x = d0; pk.y = d1; pk.z = d2; pk.w = d3;
        *(uint4*)&As[buf][ar * 64 + as_ * 8] = pk;
    };
    auto stageB = [&](int k0, int buf) {
#pragma unroll
        for (int i = 0; i < 3; ++i) {
            int slot0 = i * 512 + w * 64;               // wave-uniform base unit
            int n = i * 64 + w * 8 + (lane >> 3);
            int us = (lane & 7) ^ (lane >> 3);
            gload_lds16(wt + (size_t)n * 1024 + k0 + us * 8,
                        &Bs[buf][slot0 * 8]);
        }
    };

    // prologue: tiles 0,1 staged; A sets 0,1 loaded; A tile 0 written
    stageB(0, 0);
    stageB(64, 1);
    sloadA(0, 0);
    sloadA(1, 64);
    swriteA(0, 0);
    __syncthreads();          // one-time full drain

    for (int kt = 0; kt < 16; ++kt) {
        const int cur = kt & 1;
        const int b3 = kt % 3;
        if (kt < 14) {
            stageB((kt + 2) * 64, (kt + 2) % 3);   // async, 2-step in-flight window
            sloadA(cur, (kt + 2) * 64);            // dist-2 A reg prefetch
        }
#pragma unroll
        for (int ks = 0; ks < 2; ++ks) {
            u16x8 a0 = *(const u16x8*)&As[cur][((w & 1) * 16 + l15) * 64 +
                                               (((ks * 4 + g) ^ (l15 & 7)) * 8)];
            u16x8 a1 = *(const u16x8*)&As[cur][(32 + (w & 1) * 16 + l15) * 64 +
                                               (((ks * 4 + g) ^ (l15 & 7)) * 8)];
#pragma unroll
            for (int nf = 0; nf < 3; ++nf) {
                int n = (w >> 1) * 48 + nf * 16 + l15;
                u16x8 b = *(const u16x8*)&Bs[b3][n * 64 + (((ks * 4 + g) ^ (n & 7)) * 8)];
                acc[0][nf] = mfma16(a0, b, acc[0][nf]);
                acc[1][nf] = mfma16(a1, b, acc[1][nf]);
            }
        }
        if (kt < 15) {
            swriteA(cur ^ 1, cur ^ 1);             // A tile kt+1 -> LDS
            // counted wait: stageB(kt+1) (older than newest 5) must be done in
            // THIS wave before its barrier; this step's 5 vmem ops stay in flight.
            if (kt < 14)
                asm volatile("s_waitcnt vmcnt(5) lgkmcnt(0)" ::: "memory");
            else
                asm volatile("s_waitcnt vmcnt(0) lgkmcnt(0)" ::: "memory");
            __builtin_amdgcn_s_barrier();
        }
    }

    // epilogue: D layout col=lane&15, row=g*4+reg
#pragma unroll
    for (int nf = 0; nf < 3; ++nf) {
        int nb = (w >> 1) * 3 + nf;
        int arr = nb >> 2;
        int nloc = ((nb & 3) << 4) + l15;
#pragma unroll
        for (int mi = 0; mi < 2; ++mi) {
            f32x4 ac = acc[mi][nf];
            int row = m0 + mi * 32 + (w & 1) * 16 + g * 4;
            if (arr == 2) {
                u16x4 pk = {f2bf(ac[0]), f2bf(ac[1]), f2bf(ac[2]), f2bf(ac[3])};
                *(u16x4*)&vtw[(size_t)nloc * BT_ + row] = pk;
            } else {
                unsigned short* dst = arr ? qw : kw;
                dst[(size_t)(row + 0) * 64 + nloc] = f2bf(ac[0]);
                dst[(size_t)(row + 1) * 64 + nloc] = f2bf(ac[1]);
                dst[(size_t)(row + 2) * 64 + nloc] = f2bf(ac[2]);
                dst[(size_t)(row + 3) * 64 + nloc] = f2bf(ac[3]);
            }
        }
    }
}

// ---------------------------------------------------------------------------
// Kernel 3 (v10): attention partials — round-16 exact (DMA staging + bf16
// partials, unchanged to isolate proj's delta). grid 256 x 512.
// ---------------------------------------------------------------------------
__global__ __launch_bounds__(512, 2) void attn_part(const unsigned short* __restrict__ kw,
                                                    const unsigned short* __restrict__ qw,
                                                    const unsigned short* __restrict__ vtw,
                                                    unsigned short* __restrict__ Opart,
                                                    float* __restrict__ lpart) {
    __shared__ unsigned short q_s[2][64 * 64];   // 16 KB
    __shared__ unsigned short v_s[2][64 * 64];   // 16 KB
    __shared__ unsigned short p_s[8 * 32 * 64];  // 32 KB (per-wave P transpose)
    const int tid = threadIdx.x;
    const int w = tid >> 6, lane = tid & 63;
    const int g = lane >> 4, l15 = lane & 15;
    const int bid = blockIdx.x;
    const int b = bid & 7;                  // XCD-local batch
    const int rem = bid >> 3;               // 0..31
    const int j = (rem < 10) ? (rem / 5) : (rem < 26 ? (rem - 2) >> 2 : (rem - 8) / 3);
    const int P = Pof(j);
    const int part = rem - offsof(j);
    const size_t base = (size_t)b * T_;
    const int tA0 = 128 * j + 16 * w;
    const int tB0 = 128 * (15 - j) + 16 * w;
    const int nS = 2 * (16 - j);            // s-tiles covering tile B's range
    unsigned short* p_my = p_s + w * 2048;
    const float SCL = 0.125f * 1.44269504f;
    const float MOFF = 16.0f;

    // k fragments (tf=0 -> tile A rows, tf=1 -> tile B rows)
    u16x8 kf[2][2];
#pragma unroll
    for (int tf = 0; tf < 2; ++tf) {
        const unsigned short* kr = kw + (size_t)(base + (tf ? tB0 : tA0) + l15) * 64;
        kf[tf][0] = *(const u16x8*)(kr + g * 8);
        kf[tf][1] = *(const u16x8*)(kr + 32 + g * 8);
    }

    f32x4 o[4][2] = {};
    float l_lane[2] = {0.f, 0.f};

    // DMA staging: wave w covers rows w*8..w*8+7; source unit (l&7)^(r&7).
    auto stageQV = [&](int st, int buf) {
        int s0 = st << 6;
        int r = w * 8 + (lane >> 3);
        int us = (lane & 7) ^ (lane >> 3);
        gload_lds16(qw + (size_t)(base + s0 + r) * 64 + us * 8,
                    &q_s[buf][w * 512]);
        gload_lds16(vtw + (size_t)r * BT_ + base + s0 + us * 8,
                    &v_s[buf][w * 512]);
    };

    stageQV(part, 0);
    __syncthreads();

    int i = 0;
    for (int st = part; st < nS; st += P, ++i) {
        const int s0 = st << 6;
        const int buf = i & 1;
        const bool more = (st + P < nS);
        if (more) stageQV(st + P, buf ^ 1);   // async DMA into back buffer
        const bool dA = (s0 <= tA0 + 15);
        const bool dB = (s0 <= tB0 + 15);

        // ---- a-frags from shared q tile (used by both tf) ----
        u16x8 a[2][4];
#pragma unroll
        for (int ks = 0; ks < 2; ++ks)
#pragma unroll
            for (int sf = 0; sf < 4; ++sf)
                a[ks][sf] = *(const u16x8*)&q_s[buf][(sf * 16 + l15) * 64 +
                                                     (((ks * 4 + g) ^ (l15 & 7)) * 8)];

        // ---- QK^T ----
        f32x4 s_[4][2] = {};
        __builtin_amdgcn_s_setprio(1);
        if (dB) {
#pragma unroll
            for (int ks = 0; ks < 2; ++ks)
#pragma unroll
                for (int sf = 0; sf < 4; ++sf)
                    s_[sf][1] = mfma16(a[ks][sf], kf[1][ks], s_[sf][1]);
        }
        if (dA) {
#pragma unroll
            for (int ks = 0; ks < 2; ++ks)
#pragma unroll
                for (int sf = 0; sf < 4; ++sf)
                    s_[sf][0] = mfma16(a[ks][sf], kf[0][ks], s_[sf][0]);
        }
        __builtin_amdgcn_s_setprio(0);

        // ---- static-max softmax + p pack (verified path) ----
#pragma unroll
        for (int tf_ = 1; tf_ >= 0; --tf_) {
            if (tf_ ? !dB : !dA) continue;
            const int tbase_ = tf_ ? tB0 : tA0;
            float pv[4][4];
#pragma unroll
            for (int sf = 0; sf < 4; ++sf)
#pragma unroll
                for (int r = 0; r < 4; ++r)
                    pv[sf][r] = exp2f(fmaf(s_[sf][tf_][r], SCL, -MOFF));
            if (s0 + 63 > tbase_) {
                const int t_ = tbase_ + l15;
#pragma unroll
                for (int sf = 0; sf < 4; ++sf)
#pragma unroll
                    for (int r = 0; r < 4; ++r) {
                        int sg = s0 + sf * 16 + g * 4 + r;
                        if (sg > t_) pv[sf][r] = 0.f;
                    }
            }
            float lacc = 0.f;
#pragma unroll
            for (int sf = 0; sf < 4; ++sf)
                lacc += (pv[sf][0] + pv[sf][1]) + (pv[sf][2] + pv[sf][3]);
            l_lane[tf_] += lacc;
            const int trow = tf_ * 16 + l15;
#pragma unroll
            for (int sf = 0; sf < 4; ++sf) {
                unsigned r0, r1;
                cvtpk4(pv[sf][0], pv[sf][1], pv[sf][2], pv[sf][3], r0, r1);
                int u16i = (sf * 2 + (g >> 1)) ^ (l15 & 7);
                uint2 pk; pk.x = r0; pk.y = r1;
                *(uint2*)&p_my[trow * 64 + u16i * 8 + (g & 1) * 4] = pk;
            }
        }

        // ---- PV from shared vT tile ----
        u16x8 vf[2][4];
#pragma unroll
        for (int ks = 0; ks < 2; ++ks)
#pragma unroll
            for (int mf = 0; mf < 4; ++mf)
                vf[ks][mf] = *(const u16x8*)&v_s[buf][(mf * 16 + l15) * 64 +
                                                      (((ks * 4 + g) ^ (l15 & 7)) * 8)];
        __builtin_amdgcn_s_setprio(1);
#pragma unroll
        for (int ks = 0; ks < 2; ++ks) {
            if (dB) {
                u16x8 bp1 = *(const u16x8*)&p_my[(16 + l15) * 64 +
                                                 (((ks * 4 + g) ^ (l15 & 7)) * 8)];
#pragma unroll
                for (int mf = 0; mf < 4; ++mf)
                    o[mf][1] = mfma16(vf[ks][mf], bp1, o[mf][1]);
            }
            if (dA) {
                u16x8 bp0 = *(const u16x8*)&p_my[l15 * 64 +
                                                 (((ks * 4 + g) ^ (l15 & 7)) * 8)];
#pragma unroll
                for (int mf = 0; mf < 4; ++mf)
                    o[mf][0] = mfma16(vf[ks][mf], bp0, o[mf][0]);
            }
        }
        __builtin_amdgcn_s_setprio(0);

        __syncthreads();
    }

    // ---- store partials (bf16): O^T lanes col=t, rows h contiguous ----
#pragma unroll
    for (int tf = 0; tf < 2; ++tf) {
        float ls = l_lane[tf];
        ls += __shfl_xor(ls, 16);
        ls += __shfl_xor(ls, 32);
        int rl = tf * 128 + w * 16 + l15;     // row_local 0..255
        if (g == 0) lpart[(size_t)bid * 256 + rl] = ls;
#pragma unroll
        for (int mf = 0; mf < 4; ++mf) {
            unsigned r0, r1;
            cvtpk4(o[mf][tf][0], o[mf][tf][1], o[mf][tf][2], o[mf][tf][3], r0, r1);
            uint2 pk; pk.x = r0; pk.y = r1;
            *(uint2*)&Opart[(size_t)bid * 16384 + (size_t)rl * 64 + mf * 16 + g * 4] = pk;
        }
    }
}

// ---------------------------------------------------------------------------
// Kernel 4: combine P(j) s-partials (bf16 in, f32 out): out = sum(O)/sum(l).
// grid 1024 x 256; thread -> (row, 4 h-cols).
// ---------------------------------------------------------------------------
__global__ __launch_bounds__(256) void attn_comb(const unsigned short* __restrict__ Opart,
                                                 const float* __restrict__ lpart,
                                                 float* __restrict__ out) {
    int gt = blockIdx.x * 256 + threadIdx.x;
    int row = gt >> 4;                // 0..16383 = b*2048 + t
    int h0 = (gt & 15) << 2;
    int b = row >> 11, t = row & 2047;
    int ti = t >> 7, rit = t & 127;
    int j = (ti < 8) ? ti : (15 - ti);
    int tf = (ti < 8) ? 0 : 1;
    int rl = tf * 128 + rit;
    int P = Pof(j), offs = offsof(j);
    f32x4 acc = {};
    float L = 0.f;
    for (int p = 0; p < P; ++p) {
        int pb = b + 8 * (offs + p);
        u16x4 ov = *(const u16x4*)&Opart[(size_t)pb * 16384 + (size_t)rl * 64 + h0];
        acc += bf4f(ov);
        L += lpart[(size_t)pb * 256 + rl];
    }
    float inv = 1.f / L;
    *(f32x4*)&out[(size_t)row * 64 + h0] = acc * inv;
}

// ---------------------------------------------------------------------------
extern "C" void kernel_launch(void* const* d_in, const int* in_sizes, int n_in,
                              void* d_out, int out_size, void* d_ws, size_t ws_size,
                              hipStream_t stream) {
    const float* idx = (const float*)d_in[0];
    const float* Wk = (const float*)d_in[1];
    const float* Wq = (const float*)d_in[2];
    const float* Wv = (const float*)d_in[3];
    float* out = (float*)d_out;

    // ws: bf16 region [wt | kw | qw | vtw] (6.7 MB); partials at 8 MB (bf16 O + f32 l)
    unsigned short* wt = (unsigned short*)d_ws;
    unsigned short* kw = wt + 192 * 1024;
    unsigned short* qw = kw + (size_t)BT_ * 64;
    unsigned short* vtw = qw + (size_t)BT_ * 64;
    unsigned short* Opart = (unsigned short*)((char*)d_ws + (8u << 20));  // 8.4 MB bf16
    float* lpart = (float*)((char*)d_ws + (18u << 20));                   // 256KB f32

    wprep<<<48, 256, 0, stream>>>(Wk, Wq, Wv, wt);
    proj_gemm<<<256, 512, 0, stream>>>(idx, wt, kw, qw, vtw);
    attn_part<<<256, 512, 0, stream>>>(kw, qw, vtw, Opart, lpart);
    attn_comb<<<1024, 256, 0, stream>>>(Opart, lpart, out);
}

// Round 21
// 46.160 us; speedup vs baseline: 2.3092x; 1.0032x over previous
//
#include <hip/hip_runtime.h>

#define B_ 8
#define T_ 2048
#define C_ 1024
#define H_ 64
#define BT_ (B_ * T_)

typedef float f32x4 __attribute__((ext_vector_type(4)));
typedef unsigned short u16x4 __attribute__((ext_vector_type(4)));
typedef unsigned short u16x8 __attribute__((ext_vector_type(8)));
typedef __bf16 bf16x8 __attribute__((ext_vector_type(8)));

// f32 -> bf16 round-to-nearest-even
static __device__ __forceinline__ unsigned short f2bf(float f) {
    unsigned int u = __builtin_bit_cast(unsigned int, f);
    u = (u + 0x7FFFu + ((u >> 16) & 1u)) >> 16;
    return (unsigned short)u;
}

static __device__ __forceinline__ f32x4 mfma16(u16x8 a, u16x8 b, f32x4 c) {
    return __builtin_amdgcn_mfma_f32_16x16x32_bf16(
        __builtin_bit_cast(bf16x8, a), __builtin_bit_cast(bf16x8, b), c, 0, 0, 0);
}

// pack 4 f32 -> 4 bf16 (RNE) via v_cvt_pk
static __device__ __forceinline__ void cvtpk4(float a0, float a1, float a2, float a3,
                                              unsigned& d0, unsigned& d1) {
    asm("v_cvt_pk_bf16_f32 %0, %1, %2" : "=v"(d0) : "v"(a0), "v"(a1));
    asm("v_cvt_pk_bf16_f32 %0, %1, %2" : "=v"(d1) : "v"(a2), "v"(a3));
}

// bf16x4 -> f32x4
static __device__ __forceinline__ f32x4 bf4f(u16x4 v) {
    f32x4 r;
    r[0] = __builtin_bit_cast(float, (unsigned)v[0] << 16);
    r[1] = __builtin_bit_cast(float, (unsigned)v[1] << 16);
    r[2] = __builtin_bit_cast(float, (unsigned)v[2] << 16);
    r[3] = __builtin_bit_cast(float, (unsigned)v[3] << 16);
    return r;
}

// async global->LDS DMA, 16B per lane (uintptr_t AS-cast)
static __device__ __forceinline__ void gload_lds16(const void* g, void* l) {
    auto gp = (const __attribute__((address_space(1))) char*)(
        reinterpret_cast<uintptr_t>(g));
    auto lp = (__attribute__((address_space(3))) char*)(
        reinterpret_cast<uintptr_t>(l));
    __builtin_amdgcn_global_load_lds(gp, lp, 16, 0, 0);
}

// partial-count schedule for attention pairs: P(j) = {5,5,4,4,4,4,3,3}
static __device__ __forceinline__ int Pof(int j) {
    return 5 - (j >= 2 ? 1 : 0) - (j >= 6 ? 1 : 0);
}
static __device__ __forceinline__ int offsof(int j) {
    return (j < 2) ? 5 * j : (j < 6 ? 4 * j + 2 : 3 * j + 8);
}

// ---------------------------------------------------------------------------
// Kernel 1: W [1024][64] f32 (x3) -> Wt [192][1024] bf16 (verified)
// ---------------------------------------------------------------------------
__global__ __launch_bounds__(256) void wprep(const float* __restrict__ Wk,
                                             const float* __restrict__ Wq,
                                             const float* __restrict__ Wv,
                                             unsigned short* __restrict__ wt) {
    __shared__ float tile[64][65];
    const int arr = blockIdx.x >> 4, ct = blockIdx.x & 15;
    const float* W = (arr == 0) ? Wk : ((arr == 1) ? Wq : Wv);
    const int tid = threadIdx.x;
    {
        int c = tid >> 2, seg = (tid & 3) << 4;
        const float* src = W + (size_t)(ct * 64 + c) * 64 + seg;
#pragma unroll
        for (int j = 0; j < 16; j += 4) {
            f32x4 v4 = *(const f32x4*)(src + j);
            tile[c][seg + j + 0] = v4[0];
            tile[c][seg + j + 1] = v4[1];
            tile[c][seg + j + 2] = v4[2];
            tile[c][seg + j + 3] = v4[3];
        }
    }
    __syncthreads();
    {
        int h = tid >> 2, cs = (tid & 3) << 4;
        unsigned short* dst = wt + (size_t)(arr * 64 + h) * 1024 + ct * 64 + cs;
#pragma unroll
        for (int j = 0; j < 16; ++j) dst[j] = f2bf(tile[cs + j][h]);
    }
}

// ---------------------------------------------------------------------------
// Kernel 2 (v12): proj GEMM = v11 + QUAD-BUFFERED B + vmcnt(8).
// v11's triple buffer still forced stageB(kt+1) to land within one step
// (vmcnt(5) at the boundary). Quad buffer issues stageB(kt+3) -> each B-DMA
// rides across TWO step boundaries before any wave waits: boundary kt<13
// waits vmcnt(8) (newer: this step's 3 B-DMA + 2 A-loads + last step's 3
// B-DMA), kt=13 vmcnt(5), kt=14 vmcnt(0). LDS 112 KB (1 block/CU).
// grid 256, 512 thr.
// ---------------------------------------------------------------------------
__global__ __launch_bounds__(512, 2) void proj_gemm(const float* __restrict__ idx,
                                                    const unsigned short* __restrict__ wt,
                                                    unsigned short* __restrict__ kw,
                                                    unsigned short* __restrict__ qw,
                                                    unsigned short* __restrict__ vtw) {
    __shared__ unsigned short As[2][64 * 64];    // 16 KB (2 m-tiles stacked)
    __shared__ unsigned short Bs[4][192 * 64];   // 96 KB (QUAD buffer)
    const int tid = threadIdx.x;
    const int lane = tid & 63, w = tid >> 6;
    const int g = lane >> 4, l15 = lane & 15;
    const int m0 = blockIdx.x * 64;
    const int ar = tid >> 3, as_ = tid & 7;      // A: 64 rows x 8 16B-units

    f32x4 acc[2][3] = {};    // [mi][nf]
    f32x4 areg[2][2];        // [set][half]

    auto sloadA = [&](int set, int k0) {
        const f32x4* src = (const f32x4*)(idx + (size_t)(m0 + ar) * 1024 + k0 +
                                          ((as_ ^ (ar & 7)) * 8));
        areg[set][0] = src[0];
        areg[set][1] = src[1];
    };
    auto swriteA = [&](int set, int buf) {
        unsigned d0, d1, d2, d3;
        cvtpk4(areg[set][0][0], areg[set][0][1], areg[set][0][2], areg[set][0][3], d0, d1);
        cvtpk4(areg[set][1][0], areg[set][1][1], areg[set][1][2], areg[set][1][3], d2, d3);
        uint4 pk; pk.x = d0; pk.y = d1; pk.z = d2; pk.w = d3;
        *(uint4*)&As[buf][ar * 64 + as_ * 8] = pk;
    };
    auto stageB = [&](int k0, int buf) {
#pragma unroll
        for (int i = 0; i < 3; ++i) {
            int slot0 = i * 512 + w * 64;               // wave-uniform base unit
            int n = i * 64 + w * 8 + (lane >> 3);
            int us = (lane & 7) ^ (lane >> 3);
            gload_lds16(wt + (size_t)n * 1024 + k0 + us * 8,
                        &Bs[buf][slot0 * 8]);
        }
    };

    // prologue: B tiles 0..2 staged; A sets 0,1 loaded; A tile 0 written
    stageB(0, 0);
    stageB(64, 1);
    stageB(128, 2);
    sloadA(0, 0);
    sloadA(1, 64);
    swriteA(0, 0);
    __syncthreads();          // one-time full drain

    for (int kt = 0; kt < 16; ++kt) {
        const int cur = kt & 1;
        const int b4 = kt & 3;
        if (kt < 13) stageB((kt + 3) * 64, (kt + 3) & 3);  // 3-ahead async stage
        if (kt < 14) sloadA(cur, (kt + 2) * 64);           // dist-2 A reg prefetch
#pragma unroll
        for (int ks = 0; ks < 2; ++ks) {
            u16x8 a0 = *(const u16x8*)&As[cur][((w & 1) * 16 + l15) * 64 +
                                               (((ks * 4 + g) ^ (l15 & 7)) * 8)];
            u16x8 a1 = *(const u16x8*)&As[cur][(32 + (w & 1) * 16 + l15) * 64 +
                                               (((ks * 4 + g) ^ (l15 & 7)) * 8)];
#pragma unroll
            for (int nf = 0; nf < 3; ++nf) {
                int n = (w >> 1) * 48 + nf * 16 + l15;
                u16x8 b = *(const u16x8*)&Bs[b4][n * 64 + (((ks * 4 + g) ^ (n & 7)) * 8)];
                acc[0][nf] = mfma16(a0, b, acc[0][nf]);
                acc[1][nf] = mfma16(a1, b, acc[1][nf]);
            }
        }
        if (kt < 15) {
            swriteA(cur ^ 1, cur ^ 1);             // A tile kt+1 -> LDS
            // counted wait: stageB(kt+1) must be complete in THIS wave before
            // its barrier; leave the two newer stageB batches + A in flight.
            if (kt < 13)
                asm volatile("s_waitcnt vmcnt(8) lgkmcnt(0)" ::: "memory");
            else if (kt < 14)
                asm volatile("s_waitcnt vmcnt(5) lgkmcnt(0)" ::: "memory");
            else
                asm volatile("s_waitcnt vmcnt(0) lgkmcnt(0)" ::: "memory");
            __builtin_amdgcn_s_barrier();
        }
    }

    // epilogue: D layout col=lane&15, row=g*4+reg
#pragma unroll
    for (int nf = 0; nf < 3; ++nf) {
        int nb = (w >> 1) * 3 + nf;
        int arr = nb >> 2;
        int nloc = ((nb & 3) << 4) + l15;
#pragma unroll
        for (int mi = 0; mi < 2; ++mi) {
            f32x4 ac = acc[mi][nf];
            int row = m0 + mi * 32 + (w & 1) * 16 + g * 4;
            if (arr == 2) {
                u16x4 pk = {f2bf(ac[0]), f2bf(ac[1]), f2bf(ac[2]), f2bf(ac[3])};
                *(u16x4*)&vtw[(size_t)nloc * BT_ + row] = pk;
            } else {
                unsigned short* dst = arr ? qw : kw;
                dst[(size_t)(row + 0) * 64 + nloc] = f2bf(ac[0]);
                dst[(size_t)(row + 1) * 64 + nloc] = f2bf(ac[1]);
                dst[(size_t)(row + 2) * 64 + nloc] = f2bf(ac[2]);
                dst[(size_t)(row + 3) * 64 + nloc] = f2bf(ac[3]);
            }
        }
    }
}

// ---------------------------------------------------------------------------
// Kernel 3 (v10): attention partials — round-16 exact (DMA staging + bf16
// partials, unchanged to isolate proj's delta). grid 256 x 512.
// ---------------------------------------------------------------------------
__global__ __launch_bounds__(512, 2) void attn_part(const unsigned short* __restrict__ kw,
                                                    const unsigned short* __restrict__ qw,
                                                    const unsigned short* __restrict__ vtw,
                                                    unsigned short* __restrict__ Opart,
                                                    float* __restrict__ lpart) {
    __shared__ unsigned short q_s[2][64 * 64];   // 16 KB
    __shared__ unsigned short v_s[2][64 * 64];   // 16 KB
    __shared__ unsigned short p_s[8 * 32 * 64];  // 32 KB (per-wave P transpose)
    const int tid = threadIdx.x;
    const int w = tid >> 6, lane = tid & 63;
    const int g = lane >> 4, l15 = lane & 15;
    const int bid = blockIdx.x;
    const int b = bid & 7;                  // XCD-local batch
    const int rem = bid >> 3;               // 0..31
    const int j = (rem < 10) ? (rem / 5) : (rem < 26 ? (rem - 2) >> 2 : (rem - 8) / 3);
    const int P = Pof(j);
    const int part = rem - offsof(j);
    const size_t base = (size_t)b * T_;
    const int tA0 = 128 * j + 16 * w;
    const int tB0 = 128 * (15 - j) + 16 * w;
    const int nS = 2 * (16 - j);            // s-tiles covering tile B's range
    unsigned short* p_my = p_s + w * 2048;
    const float SCL = 0.125f * 1.44269504f;
    const float MOFF = 16.0f;

    // k fragments (tf=0 -> tile A rows, tf=1 -> tile B rows)
    u16x8 kf[2][2];
#pragma unroll
    for (int tf = 0; tf < 2; ++tf) {
        const unsigned short* kr = kw + (size_t)(base + (tf ? tB0 : tA0) + l15) * 64;
        kf[tf][0] = *(const u16x8*)(kr + g * 8);
        kf[tf][1] = *(const u16x8*)(kr + 32 + g * 8);
    }

    f32x4 o[4][2] = {};
    float l_lane[2] = {0.f, 0.f};

    // DMA staging: wave w covers rows w*8..w*8+7; source unit (l&7)^(r&7).
    auto stageQV = [&](int st, int buf) {
        int s0 = st << 6;
        int r = w * 8 + (lane >> 3);
        int us = (lane & 7) ^ (lane >> 3);
        gload_lds16(qw + (size_t)(base + s0 + r) * 64 + us * 8,
                    &q_s[buf][w * 512]);
        gload_lds16(vtw + (size_t)r * BT_ + base + s0 + us * 8,
                    &v_s[buf][w * 512]);
    };

    stageQV(part, 0);
    __syncthreads();

    int i = 0;
    for (int st = part; st < nS; st += P, ++i) {
        const int s0 = st << 6;
        const int buf = i & 1;
        const bool more = (st + P < nS);
        if (more) stageQV(st + P, buf ^ 1);   // async DMA into back buffer
        const bool dA = (s0 <= tA0 + 15);
        const bool dB = (s0 <= tB0 + 15);

        // ---- a-frags from shared q tile (used by both tf) ----
        u16x8 a[2][4];
#pragma unroll
        for (int ks = 0; ks < 2; ++ks)
#pragma unroll
            for (int sf = 0; sf < 4; ++sf)
                a[ks][sf] = *(const u16x8*)&q_s[buf][(sf * 16 + l15) * 64 +
                                                     (((ks * 4 + g) ^ (l15 & 7)) * 8)];

        // ---- QK^T ----
        f32x4 s_[4][2] = {};
        __builtin_amdgcn_s_setprio(1);
        if (dB) {
#pragma unroll
            for (int ks = 0; ks < 2; ++ks)
#pragma unroll
                for (int sf = 0; sf < 4; ++sf)
                    s_[sf][1] = mfma16(a[ks][sf], kf[1][ks], s_[sf][1]);
        }
        if (dA) {
#pragma unroll
            for (int ks = 0; ks < 2; ++ks)
#pragma unroll
                for (int sf = 0; sf < 4; ++sf)
                    s_[sf][0] = mfma16(a[ks][sf], kf[0][ks], s_[sf][0]);
        }
        __builtin_amdgcn_s_setprio(0);

        // ---- static-max softmax + p pack (verified path) ----
#pragma unroll
        for (int tf_ = 1; tf_ >= 0; --tf_) {
            if (tf_ ? !dB : !dA) continue;
            const int tbase_ = tf_ ? tB0 : tA0;
            float pv[4][4];
#pragma unroll
            for (int sf = 0; sf < 4; ++sf)
#pragma unroll
                for (int r = 0; r < 4; ++r)
                    pv[sf][r] = exp2f(fmaf(s_[sf][tf_][r], SCL, -MOFF));
            if (s0 + 63 > tbase_) {
                const int t_ = tbase_ + l15;
#pragma unroll
                for (int sf = 0; sf < 4; ++sf)
#pragma unroll
                    for (int r = 0; r < 4; ++r) {
                        int sg = s0 + sf * 16 + g * 4 + r;
                        if (sg > t_) pv[sf][r] = 0.f;
                    }
            }
            float lacc = 0.f;
#pragma unroll
            for (int sf = 0; sf < 4; ++sf)
                lacc += (pv[sf][0] + pv[sf][1]) + (pv[sf][2] + pv[sf][3]);
            l_lane[tf_] += lacc;
            const int trow = tf_ * 16 + l15;
#pragma unroll
            for (int sf = 0; sf < 4; ++sf) {
                unsigned r0, r1;
                cvtpk4(pv[sf][0], pv[sf][1], pv[sf][2], pv[sf][3], r0, r1);
                int u16i = (sf * 2 + (g >> 1)) ^ (l15 & 7);
                uint2 pk; pk.x = r0; pk.y = r1;
                *(uint2*)&p_my[trow * 64 + u16i * 8 + (g & 1) * 4] = pk;
            }
        }

        // ---- PV from shared vT tile ----
        u16x8 vf[2][4];
#pragma unroll
        for (int ks = 0; ks < 2; ++ks)
#pragma unroll
            for (int mf = 0; mf < 4; ++mf)
                vf[ks][mf] = *(const u16x8*)&v_s[buf][(mf * 16 + l15) * 64 +
                                                      (((ks * 4 + g) ^ (l15 & 7)) * 8)];
        __builtin_amdgcn_s_setprio(1);
#pragma unroll
        for (int ks = 0; ks < 2; ++ks) {
            if (dB) {
                u16x8 bp1 = *(const u16x8*)&p_my[(16 + l15) * 64 +
                                                 (((ks * 4 + g) ^ (l15 & 7)) * 8)];
#pragma unroll
                for (int mf = 0; mf < 4; ++mf)
                    o[mf][1] = mfma16(vf[ks][mf], bp1, o[mf][1]);
            }
            if (dA) {
                u16x8 bp0 = *(const u16x8*)&p_my[l15 * 64 +
                                                 (((ks * 4 + g) ^ (l15 & 7)) * 8)];
#pragma unroll
                for (int mf = 0; mf < 4; ++mf)
                    o[mf][0] = mfma16(vf[ks][mf], bp0, o[mf][0]);
            }
        }
        __builtin_amdgcn_s_setprio(0);

        __syncthreads();
    }

    // ---- store partials (bf16): O^T lanes col=t, rows h contiguous ----
#pragma unroll
    for (int tf = 0; tf < 2; ++tf) {
        float ls = l_lane[tf];
        ls += __shfl_xor(ls, 16);
        ls += __shfl_xor(ls, 32);
        int rl = tf * 128 + w * 16 + l15;     // row_local 0..255
        if (g == 0) lpart[(size_t)bid * 256 + rl] = ls;
#pragma unroll
        for (int mf = 0; mf < 4; ++mf) {
            unsigned r0, r1;
            cvtpk4(o[mf][tf][0], o[mf][tf][1], o[mf][tf][2], o[mf][tf][3], r0, r1);
            uint2 pk; pk.x = r0; pk.y = r1;
            *(uint2*)&Opart[(size_t)bid * 16384 + (size_t)rl * 64 + mf * 16 + g * 4] = pk;
        }
    }
}

// ---------------------------------------------------------------------------
// Kernel 4: combine P(j) s-partials (bf16 in, f32 out): out = sum(O)/sum(l).
// grid 1024 x 256; thread -> (row, 4 h-cols).
// ---------------------------------------------------------------------------
__global__ __launch_bounds__(256) void attn_comb(const unsigned short* __restrict__ Opart,
                                                 const float* __restrict__ lpart,
                                                 float* __restrict__ out) {
    int gt = blockIdx.x * 256 + threadIdx.x;
    int row = gt >> 4;                // 0..16383 = b*2048 + t
    int h0 = (gt & 15) << 2;
    int b = row >> 11, t = row & 2047;
    int ti = t >> 7, rit = t & 127;
    int j = (ti < 8) ? ti : (15 - ti);
    int tf = (ti < 8) ? 0 : 1;
    int rl = tf * 128 + rit;
    int P = Pof(j), offs = offsof(j);
    f32x4 acc = {};
    float L = 0.f;
    for (int p = 0; p < P; ++p) {
        int pb = b + 8 * (offs + p);
        u16x4 ov = *(const u16x4*)&Opart[(size_t)pb * 16384 + (size_t)rl * 64 + h0];
        acc += bf4f(ov);
        L += lpart[(size_t)pb * 256 + rl];
    }
    float inv = 1.f / L;
    *(f32x4*)&out[(size_t)row * 64 + h0] = acc * inv;
}

// ---------------------------------------------------------------------------
extern "C" void kernel_launch(void* const* d_in, const int* in_sizes, int n_in,
                              void* d_out, int out_size, void* d_ws, size_t ws_size,
                              hipStream_t stream) {
    const float* idx = (const float*)d_in[0];
    const float* Wk = (const float*)d_in[1];
    const float* Wq = (const float*)d_in[2];
    const float* Wv = (const float*)d_in[3];
    float* out = (float*)d_out;

    // ws: bf16 region [wt | kw | qw | vtw] (6.7 MB); partials at 8 MB (bf16 O + f32 l)
    unsigned short* wt = (unsigned short*)d_ws;
    unsigned short* kw = wt + 192 * 1024;
    unsigned short* qw = kw + (size_t)BT_ * 64;
    unsigned short* vtw = qw + (size_t)BT_ * 64;
    unsigned short* Opart = (unsigned short*)((char*)d_ws + (8u << 20));  // 8.4 MB bf16
    float* lpart = (float*)((char*)d_ws + (18u << 20));                   // 256KB f32

    wprep<<<48, 256, 0, stream>>>(Wk, Wq, Wv, wt);
    proj_gemm<<<256, 512, 0, stream>>>(idx, wt, kw, qw, vtw);
    attn_part<<<256, 512, 0, stream>>>(kw, qw, vtw, Opart, lpart);
    attn_comb<<<1024, 256, 0, stream>>>(Opart, lpart, out);
}